// Round 13
// baseline (238.202 us; speedup 1.0000x reference)
//
#include <hip/hip_runtime.h>

#define SN 6400      // H*W
#define CN 256       // channels (= GEMM K)
#define NBATCH 2
#define NTILES 50    // SN / 128 (fixed-side row tiles, GEMM)
#define NCHUNK 5     // streamed-side chunks (GEMM grid = 50*5*2 = 500 blocks)
#define TPC 5        // 256-wide streamed tiles per chunk
#define NJC 25       // streaming j-chunks (6400/256)
#define NIP 25       // i/j panels of 256

typedef _Float16 f16;
typedef f16 f16x8 __attribute__((ext_vector_type(8)));
typedef f16 f16x4 __attribute__((ext_vector_type(4)));
typedef float f32x4 __attribute__((ext_vector_type(4)));

__device__ __forceinline__ void gld16(const f16* g, f16* l) {
    __builtin_amdgcn_global_load_lds(
        (__attribute__((address_space(1))) void*)(g),
        (__attribute__((address_space(3))) void*)(l), 16, 0, 0);
}

// Stage a 256-row x 64-half (32 KB) K-chunk into LDS with 512 threads
// (4 gld16/thread). XOR source swizzle; verified conflict-free (R0-R12).
__device__ __forceinline__ void stageB(const f16* __restrict__ g,
                                       f16* l, int tid) {
    #pragma unroll
    for (int it = 0; it < 4; ++it) {
        int q = it * 512 + tid;
        int row = q >> 3, c = q & 7;
        int cg = c ^ (row & 7);
        gld16(g + (size_t)row * CN + cg * 8, l + (q & ~63) * 8);
    }
}

// ---------------- prep kernels ----------------

__global__ __launch_bounds__(256) void k_meanT(const float* __restrict__ T,
                                               float* __restrict__ meanT) {
    int c = blockIdx.x, t = threadIdx.x;
    const float* p0 = T + (size_t)c * SN;
    const float* p1 = T + (size_t)(CN + c) * SN;
    float s = 0.f;
    for (int i = t; i < SN; i += 256) s += p0[i] + p1[i];
    #pragma unroll
    for (int d = 1; d < 64; d <<= 1) s += __shfl_xor(s, d, 64);
    __shared__ float sb[4];
    if ((t & 63) == 0) sb[t >> 6] = s;
    __syncthreads();
    if (t == 0) meanT[c] = (sb[0] + sb[1] + sb[2] + sb[3]) * (1.0f / 12800.0f);
}

// FUSED center + transpose + L2-normalize: [n,c,s] f32 -> [n,s,c] f16 unit
// rows. R13: write-phase LDS read had a 16-way bank conflict (row stride
// 4*66 = 8 mod 32 -> 4 banks). Now lane reads c = lane + 64k: bank
// (2*lane+s)%32 -> 2 lanes/bank = free; global store is 64x2B = 128 B
// contiguous per instruction (still coalesced).
__global__ __launch_bounds__(256) void k_prep(const float* __restrict__ X,
                                              const float* __restrict__ meanT,
                                              f16* __restrict__ out) {
    const int n = blockIdx.z, s0 = blockIdx.x * 64;
    const int t = threadIdx.x, lane = t & 63, w = t >> 6;
    __shared__ float tile[256][66];   // 67.6 KB
    __shared__ float red[64][4];
    __shared__ float rsq[64];

    const float* Xn = X + (size_t)n * CN * SN;
    // load + center: 16 iters x 16 rows; float4 per lane (16 lanes/row)
    #pragma unroll 4
    for (int it = 0; it < 16; ++it) {
        int c = it * 16 + w * 4 + (lane >> 4);
        const float4 v = *(const float4*)&Xn[(size_t)c * SN + s0 + (lane & 15) * 4];
        float mc = meanT[c];
        int col = (lane & 15) * 4;
        tile[c][col + 0] = v.x - mc;
        tile[c][col + 1] = v.y - mc;
        tile[c][col + 2] = v.z - mc;
        tile[c][col + 3] = v.w - mc;
    }
    __syncthreads();
    // per-s sum of squares: thread t -> s = t&63, quarter q = t>>6
    {
        int s = t & 63, q = t >> 6;
        float acc = 0.f;
        #pragma unroll 8
        for (int c = q * 64; c < q * 64 + 64; ++c) {
            float x = tile[c][s];
            acc = fmaf(x, x, acc);
        }
        red[s][q] = acc;
    }
    __syncthreads();
    if (t < 64) rsq[t] = rsqrtf(red[t][0] + red[t][1] + red[t][2] + red[t][3]);
    __syncthreads();
    // write [s][c] f16: wave w handles rows s = w*16 .. w*16+15;
    // lane covers c = lane, lane+64, lane+128, lane+192 (conflict-free)
    f16* on = out + ((size_t)n * SN + s0) * CN;
    #pragma unroll 4
    for (int r = 0; r < 16; ++r) {
        int s = w * 16 + r;
        float sc = rsq[s];
        #pragma unroll
        for (int k = 0; k < 4; ++k) {
            int c = lane + 64 * k;
            on[(size_t)s * CN + c] = (f16)(tile[c][s] * sc);
        }
    }
}

// ---------------- pass 0: GEMM (R3 structure) + cache S (R12 verbatim) ----
__global__ __launch_bounds__(512, 1) void k_gemm_s(const f16* __restrict__ A,
                                                   const f16* __restrict__ B,
                                                   float* __restrict__ outP,
                                                   f16* __restrict__ Sws) {
    const int n = blockIdx.z, chunk = blockIdx.y, ft = blockIdx.x;
    const int tid = threadIdx.x, lane = tid & 63, wv = tid >> 6;
    const int quad = lane >> 4, lrow = lane & 15;
    const int wr4 = wv >> 2, wc4 = wv & 3;

    __shared__ f16 Abuf[4][128 * 64];   // 64 KB persistent A tile (h-major)
    __shared__ f16 Bb[2][256 * 64];     // 2 x 32 KB double-buffered B stage

    const f16* At = A + ((size_t)n * SN + (size_t)ft * 128) * CN;
    const f16* Bc = B + ((size_t)n * SN + (size_t)chunk * (TPC * 256)) * CN;
    f16* Sn = Sws + (size_t)n * SN * SN;
    const int ibase_th = ft * 128 + wr4 * 64 + quad * 4;

    #pragma unroll
    for (int h = 0; h < 4; ++h) {
        #pragma unroll
        for (int it = 0; it < 2; ++it) {
            int q = it * 512 + tid;
            int row = q >> 3, c = q & 7;
            int cg = c ^ (row & 7);
            gld16(At + (size_t)row * CN + h * 64 + cg * 8,
                  Abuf[h] + (q & ~63) * 8);
        }
    }
    stageB(Bc, Bb[0], tid);
    stageB(Bc + 64, Bb[1], tid);

    int offA[4][2], offB[4][2];
    #pragma unroll
    for (int i = 0; i < 4; ++i) {
        int ra = wr4 * 64 + i * 16 + lrow;
        int rb = wc4 * 64 + i * 16 + lrow;
        #pragma unroll
        for (int kk = 0; kk < 2; ++kk) {
            offA[i][kk] = ra * 64 + (((kk * 4 + quad) ^ (ra & 7)) * 8);
            offB[i][kk] = rb * 64 + (((kk * 4 + quad) ^ (rb & 7)) * 8);
        }
    }

    float runRow[4][4];
    #pragma unroll
    for (int mt = 0; mt < 4; ++mt)
        #pragma unroll
        for (int v = 0; v < 4; ++v) runRow[mt][v] = -3.0e38f;

    asm volatile("s_waitcnt vmcnt(4)" ::: "memory");
    __builtin_amdgcn_s_barrier();

#define BAR()    __builtin_amdgcn_s_barrier()
#define WAIT4()  asm volatile("s_waitcnt vmcnt(4)" ::: "memory")
#define WAIT20() asm volatile("s_waitcnt vmcnt(20)" ::: "memory")
#define WAIT0()  asm volatile("s_waitcnt vmcnt(0)" ::: "memory")

#define STAGE(h, bi)                                                      \
    { _Pragma("unroll")                                                   \
      for (int kk = 0; kk < 2; ++kk) {                                    \
          f16x8 af[4], bf[4];                                             \
          _Pragma("unroll")                                               \
          for (int mt = 0; mt < 4; ++mt)                                  \
              af[mt] = *(const f16x8*)&Abuf[h][offA[mt][kk]];             \
          _Pragma("unroll")                                               \
          for (int nt = 0; nt < 4; ++nt)                                  \
              bf[nt] = *(const f16x8*)&Bb[bi][offB[nt][kk]];              \
          _Pragma("unroll")                                               \
          for (int mt = 0; mt < 4; ++mt)                                  \
              _Pragma("unroll")                                           \
              for (int nt = 0; nt < 4; ++nt)                              \
                  acc[mt][nt] = __builtin_amdgcn_mfma_f32_16x16x32_f16(   \
                      af[mt], bf[nt], acc[mt][nt], 0, 0, 0);              \
      } }

#define EPILOGUE_S(T)                                                     \
    { int jb = (chunk * TPC + (T)) * 256;                                 \
      f16* Sth = Sn + (size_t)(jb + wc4 * 64 + lrow) * SN + ibase_th;     \
      _Pragma("unroll")                                                   \
      for (int mt = 0; mt < 4; ++mt)                                      \
          _Pragma("unroll")                                               \
          for (int nt = 0; nt < 4; ++nt) {                                \
              f16x4 hq;                                                   \
              _Pragma("unroll")                                           \
              for (int v = 0; v < 4; ++v) hq[v] = (f16)acc[mt][nt][v];    \
              *(f16x4*)(Sth + (size_t)nt * 16 * SN + mt * 16) = hq;       \
              _Pragma("unroll")                                           \
              for (int v = 0; v < 4; ++v)                                 \
                  runRow[mt][v] = fmaxf(runRow[mt][v], (float)hq[v]);     \
          } }

    f32x4 acc[4][4];

    #pragma unroll 1
    for (int t = 0; t < TPC - 1; ++t) {
        const f16* Bt = Bc + (size_t)t * (256 * CN);

        #pragma unroll
        for (int mt = 0; mt < 4; ++mt)
            #pragma unroll
            for (int nt = 0; nt < 4; ++nt) acc[mt][nt] = (f32x4){0.f, 0.f, 0.f, 0.f};

        STAGE(0, 0) BAR(); stageB(Bt + 128, Bb[0], tid);
        if (t == 0) { WAIT4(); } else { WAIT20(); }
        BAR();
        STAGE(1, 1) BAR(); stageB(Bt + 192, Bb[1], tid);            WAIT4(); BAR();
        STAGE(2, 0) BAR(); stageB(Bt + 256 * CN, Bb[0], tid);       WAIT4(); BAR();
        STAGE(3, 1) BAR(); stageB(Bt + 256 * CN + 64, Bb[1], tid);
        EPILOGUE_S(t);                                              WAIT20(); BAR();
    }

    {
        const int t = TPC - 1;
        const f16* Bt = Bc + (size_t)t * (256 * CN);

        #pragma unroll
        for (int mt = 0; mt < 4; ++mt)
            #pragma unroll
            for (int nt = 0; nt < 4; ++nt) acc[mt][nt] = (f32x4){0.f, 0.f, 0.f, 0.f};

        STAGE(0, 0) BAR(); stageB(Bt + 128, Bb[0], tid); WAIT20(); BAR();
        STAGE(1, 1) BAR(); stageB(Bt + 192, Bb[1], tid); WAIT4();  BAR();
        STAGE(2, 0) WAIT0(); BAR();
        STAGE(3, 1)
        EPILOGUE_S(t);
    }
#undef STAGE
#undef EPILOGUE_S
#undef BAR
#undef WAIT4
#undef WAIT20
#undef WAIT0

    __syncthreads();
    float* red = (float*)&Bb[0][0];
    #pragma unroll
    for (int mt = 0; mt < 4; ++mt)
        #pragma unroll
        for (int v = 0; v < 4; ++v) {
            float val = runRow[mt][v];
            #pragma unroll
            for (int d = 1; d < 16; d <<= 1)
                val = fmaxf(val, __shfl_xor(val, d, 64));
            if (lrow == 0) red[wc4 * 128 + wr4 * 64 + mt * 16 + quad * 4 + v] = val;
        }
    __syncthreads();
    if (tid < 128) {
        float a = red[tid], b = red[128 + tid];
        float c = red[256 + tid], d = red[384 + tid];
        outP[(size_t)(n * NCHUNK + chunk) * SN + ft * 128 + tid] =
            fmaxf(fmaxf(a, b), fmaxf(c, d));
    }
}

// ---------------- fallback 3-pass GEMM (R3 verbatim) ----------------
template <int PASS>
__global__ __launch_bounds__(512, 2) void k_gemm3(const f16* __restrict__ A,
                                                  const f16* __restrict__ B,
                                                  const float* __restrict__ grow,
                                                  const float* __restrict__ alpha,
                                                  float* __restrict__ outP) {
    const int n = blockIdx.z, chunk = blockIdx.y, ft = blockIdx.x;
    const int tid = threadIdx.x, lane = tid & 63, wv = tid >> 6;
    const int wr = wv >> 2, wc = wv & 3, quad = lane >> 4, lrow = lane & 15;

    __shared__ f16 Abuf[4][128 * 64];
    __shared__ f16 Bb[2][256 * 64];

    const f16* At = A + ((size_t)n * SN + (size_t)ft * 128) * CN;
    const f16* Bc = B + ((size_t)n * SN + (size_t)chunk * (TPC * 256)) * CN;

    const float L2E = 1.44269504089f;
    const float TENL2E = 14.4269504089f;
    float a1c[4][4];
    if constexpr (PASS == 1) {
        #pragma unroll
        for (int mt = 0; mt < 4; ++mt)
            #pragma unroll
            for (int v = 0; v < 4; ++v) {
                int r = ft * 128 + wr * 64 + mt * 16 + quad * 4 + v;
                a1c[mt][v] = 0.5f * grow[(size_t)n * SN + r] * L2E;
            }
    }

    #pragma unroll
    for (int h = 0; h < 4; ++h) {
        #pragma unroll
        for (int it = 0; it < 2; ++it) {
            int q = it * 512 + tid;
            int row = q >> 3, c = q & 7;
            int cg = c ^ (row & 7);
            gld16(At + (size_t)row * CN + h * 64 + cg * 8,
                  Abuf[h] + (q & ~63) * 8);
        }
    }
    stageB(Bc, Bb[0], tid);
    stageB(Bc + 64, Bb[1], tid);

    int offA[4][2], offB[4][2];
    #pragma unroll
    for (int i = 0; i < 4; ++i) {
        int ra = wr * 64 + i * 16 + lrow;
        int rb = wc * 64 + i * 16 + lrow;
        #pragma unroll
        for (int kk = 0; kk < 2; ++kk) {
            offA[i][kk] = ra * 64 + (((kk * 4 + quad) ^ (ra & 7)) * 8);
            offB[i][kk] = rb * 64 + (((kk * 4 + quad) ^ (rb & 7)) * 8);
        }
    }

    float runRow[4][4];
    #pragma unroll
    for (int mt = 0; mt < 4; ++mt)
        #pragma unroll
        for (int v = 0; v < 4; ++v) runRow[mt][v] = (PASS == 1) ? 0.f : -3.0e38f;

    float gl[4], al[4];

    asm volatile("s_waitcnt vmcnt(4)" ::: "memory");
    __builtin_amdgcn_s_barrier();

#define BAR() __builtin_amdgcn_s_barrier()
#define WAIT4() asm volatile("s_waitcnt vmcnt(4)" ::: "memory")
#define WAIT0() asm volatile("s_waitcnt vmcnt(0)" ::: "memory")

#define STAGE(h, bi)                                                      \
    { _Pragma("unroll")                                                   \
      for (int kk = 0; kk < 2; ++kk) {                                    \
          f16x8 af[4], bf[4];                                             \
          _Pragma("unroll")                                               \
          for (int mt = 0; mt < 4; ++mt)                                  \
              af[mt] = *(const f16x8*)&Abuf[h][offA[mt][kk]];             \
          _Pragma("unroll")                                               \
          for (int nt = 0; nt < 4; ++nt)                                  \
              bf[nt] = *(const f16x8*)&Bb[bi][offB[nt][kk]];              \
          _Pragma("unroll")                                               \
          for (int mt = 0; mt < 4; ++mt)                                  \
              _Pragma("unroll")                                           \
              for (int nt = 0; nt < 4; ++nt)                              \
                  acc[mt][nt] = __builtin_amdgcn_mfma_f32_16x16x32_f16(   \
                      af[mt], bf[nt], acc[mt][nt], 0, 0, 0);              \
      } }

#define EPILOGUE()                                                        \
    if constexpr (PASS == 0) {                                            \
        _Pragma("unroll")                                                 \
        for (int mt = 0; mt < 4; ++mt)                                    \
            _Pragma("unroll")                                             \
            for (int v = 0; v < 4; ++v) {                                 \
                float m = fmaxf(fmaxf(acc[mt][0][v], acc[mt][1][v]),      \
                                fmaxf(acc[mt][2][v], acc[mt][3][v]));     \
                runRow[mt][v] = fmaxf(runRow[mt][v], m);                  \
            }                                                             \
    } else if constexpr (PASS == 1) {                                     \
        _Pragma("unroll")                                                 \
        for (int mt = 0; mt < 4; ++mt)                                    \
            _Pragma("unroll")                                             \
            for (int v = 0; v < 4; ++v) {                                 \
                float a1 = a1c[mt][v], a0 = TENL2E - a1;                  \
                float s2 = runRow[mt][v];                                 \
                _Pragma("unroll")                                         \
                for (int nt = 0; nt < 4; ++nt) {                          \
                    float arg = fminf(TENL2E,                             \
                                      fmaf(acc[mt][nt][v], a1, a0));      \
                    s2 += exp2f(arg);                                     \
                }                                                         \
                runRow[mt][v] = s2;                                       \
            }                                                             \
    } else {                                                              \
        _Pragma("unroll")                                                 \
        for (int mt = 0; mt < 4; ++mt)                                    \
            _Pragma("unroll")                                             \
            for (int v = 0; v < 4; ++v) {                                 \
                _Pragma("unroll")                                         \
                for (int nt = 0; nt < 4; ++nt) {                          \
                    float raw = fmaxf(0.f, fmaf(acc[mt][nt][v], -0.5f, 0.5f)); \
                    float lc = fmaf(-gl[nt], raw, al[nt]);                \
                    runRow[mt][v] = fmaxf(runRow[mt][v], lc);             \
                }                                                         \
            }                                                             \
    }

    f32x4 acc[4][4];

    #pragma unroll 1
    for (int t = 0; t < TPC - 1; ++t) {
        const f16* Bt = Bc + (size_t)t * (256 * CN);

        if constexpr (PASS == 2) {
            #pragma unroll
            for (int nt = 0; nt < 4; ++nt) {
                int i = (chunk * TPC + t) * 256 + wc * 64 + nt * 16 + lrow;
                gl[nt] = grow[(size_t)n * SN + i];
                al[nt] = alpha[(size_t)n * SN + i];
            }
        }

        #pragma unroll
        for (int mt = 0; mt < 4; ++mt)
            #pragma unroll
            for (int nt = 0; nt < 4; ++nt) acc[mt][nt] = (f32x4){0.f, 0.f, 0.f, 0.f};

        STAGE(0, 0) BAR(); stageB(Bt + 128, Bb[0], tid);            WAIT4(); BAR();
        STAGE(1, 1) BAR(); stageB(Bt + 192, Bb[1], tid);            WAIT4(); BAR();
        STAGE(2, 0) BAR(); stageB(Bt + 256 * CN, Bb[0], tid);       WAIT4(); BAR();
        STAGE(3, 1) BAR(); stageB(Bt + 256 * CN + 64, Bb[1], tid);
        EPILOGUE();                                                 WAIT4(); BAR();
    }

    {
        const int t = TPC - 1;
        const f16* Bt = Bc + (size_t)t * (256 * CN);

        if constexpr (PASS == 2) {
            #pragma unroll
            for (int nt = 0; nt < 4; ++nt) {
                int i = (chunk * TPC + t) * 256 + wc * 64 + nt * 16 + lrow;
                gl[nt] = grow[(size_t)n * SN + i];
                al[nt] = alpha[(size_t)n * SN + i];
            }
        }

        #pragma unroll
        for (int mt = 0; mt < 4; ++mt)
            #pragma unroll
            for (int nt = 0; nt < 4; ++nt) acc[mt][nt] = (f32x4){0.f, 0.f, 0.f, 0.f};

        STAGE(0, 0) BAR(); stageB(Bt + 128, Bb[0], tid); WAIT4(); BAR();
        STAGE(1, 1) BAR(); stageB(Bt + 192, Bb[1], tid); WAIT4(); BAR();
        STAGE(2, 0) WAIT0(); BAR();
        STAGE(3, 1)
        EPILOGUE();
    }
#undef STAGE
#undef EPILOGUE
#undef BAR
#undef WAIT4
#undef WAIT0

    __syncthreads();
    float* red = (float*)&Bb[0][0];
    #pragma unroll
    for (int mt = 0; mt < 4; ++mt)
        #pragma unroll
        for (int v = 0; v < 4; ++v) {
            float val = runRow[mt][v];
            #pragma unroll
            for (int d = 1; d < 16; d <<= 1) {
                float o = __shfl_xor(val, d, 64);
                val = (PASS == 1) ? (val + o) : fmaxf(val, o);
            }
            if (lrow == 0) red[wc * 128 + wr * 64 + mt * 16 + quad * 4 + v] = val;
        }
    __syncthreads();
    if (tid < 128) {
        float a = red[tid], b = red[128 + tid];
        float c = red[256 + tid], d = red[384 + tid];
        float r = (PASS == 1) ? (a + b + c + d)
                              : fmaxf(fmaxf(a, b), fmaxf(c, d));
        outP[(size_t)(n * NCHUNK + chunk) * SN + ft * 128 + tid] = r;
    }
}

// ---------------- streaming pass 1: per-i sum of exp over j ----------------
// v4: fused g computation (reads rowmaxP; drops the r_g kernel + one device
// sync) and 16-way j-batched loads (256 B in flight/thread, 2 outer iters).
// Same FP order as r_g -> bit-identical g.
__global__ __launch_bounds__(256) void k_rowsum(const f16* __restrict__ S,
                                                const float* __restrict__ rowmaxP,
                                                float* __restrict__ sumP) {
    const int n = blockIdx.z, ip = blockIdx.y, jc = blockIdx.x;
    const int t = threadIdx.x;
    const float L2E = 1.44269504089f;
    const float TENL2E = 14.4269504089f;

    __shared__ float gl_lds[256];
    {
        int i = ip * 256 + t;
        float m = -3.0e38f;
        #pragma unroll
        for (int ch = 0; ch < NCHUNK; ++ch)
            m = fmaxf(m, rowmaxP[(size_t)(n * NCHUNK + ch) * SN + i]);
        float mr = fmaxf(0.f, (1.f - m) * 0.5f);
        gl_lds[t] = 10.f / (mr + 1e-5f);
    }
    __syncthreads();

    const int i0 = ip * 256 + (t & 31) * 8;
    const int jb = jc * 256 + (t >> 5);
    const f16* Sn = S + (size_t)n * SN * SN;

    float c1[8], a0[8];
    #pragma unroll
    for (int k = 0; k < 8; ++k) {
        float g = gl_lds[(t & 31) * 8 + k];
        c1[k] = 0.5f * g * L2E;
        a0[k] = TENL2E - c1[k];
    }

    float s8[8];
    #pragma unroll
    for (int k = 0; k < 8; ++k) s8[k] = 0.f;

    #pragma unroll 1
    for (int jt = 0; jt < 2; ++jt) {
        f16x8 v[16];
        #pragma unroll
        for (int u = 0; u < 16; ++u)
            v[u] = *(const f16x8*)(Sn + (size_t)(jb + jt * 128 + u * 8) * SN + i0);
        #pragma unroll
        for (int u = 0; u < 16; ++u)
            #pragma unroll
            for (int k = 0; k < 8; ++k) {
                float arg = fminf(TENL2E, fmaf((float)v[u][k], c1[k], a0[k]));
                s8[k] += exp2f(arg);
            }
    }

    __shared__ float red[8][256];
    #pragma unroll
    for (int k = 0; k < 8; ++k) red[t >> 5][(t & 31) * 8 + k] = s8[k];
    __syncthreads();
    float s = 0.f;
    #pragma unroll
    for (int r = 0; r < 8; ++r) s += red[r][t];
    sumP[((size_t)n * NJC + jc) * SN + ip * 256 + t] = s;
}

// ---------------- streaming pass 2: per-j max over i ----------------
// v4: fused g + alpha computation (reads rowmaxP + sumP; drops the r_alpha
// kernel + one device sync; same FP summation order as r_alpha) and 16-way
// j-batched loads. LDS cmx reduce (conflict-free, verified R12).
__global__ __launch_bounds__(256) void k_colmax(const f16* __restrict__ S,
                                                const float* __restrict__ rowmaxP,
                                                const float* __restrict__ sumP,
                                                float* __restrict__ colmaxP) {
    const int n = blockIdx.z, ip = blockIdx.y, jc = blockIdx.x;
    const int t = threadIdx.x;

    __shared__ float gl_lds[256], al_lds[256];
    __shared__ float cmx[256][33];   // 33.8 KB

    {
        int i = ip * 256 + t;
        float m = -3.0e38f;
        #pragma unroll
        for (int ch = 0; ch < NCHUNK; ++ch)
            m = fmaxf(m, rowmaxP[(size_t)(n * NCHUNK + ch) * SN + i]);
        float mr = fmaxf(0.f, (1.f - m) * 0.5f);
        gl_lds[t] = 10.f / (mr + 1e-5f);
        float ssum = 0.f;
        for (int ch = 0; ch < NJC; ++ch)
            ssum += sumP[(size_t)(n * NJC + ch) * SN + i];
        al_lds[t] = 10.f - logf(ssum);
    }
    __syncthreads();

    const int i0 = ip * 256 + (t & 31) * 8;
    const int jb = jc * 256 + (t >> 5);
    const f16* Sn = S + (size_t)n * SN * SN;

    float gk[8], ak[8];
    #pragma unroll
    for (int k = 0; k < 8; ++k) {
        gk[k] = gl_lds[(t & 31) * 8 + k];
        ak[k] = al_lds[(t & 31) * 8 + k];
    }

    #pragma unroll 1
    for (int jt = 0; jt < 2; ++jt) {
        f16x8 v[16];
        #pragma unroll
        for (int u = 0; u < 16; ++u)
            v[u] = *(const f16x8*)(Sn + (size_t)(jb + jt * 128 + u * 8) * SN + i0);
        #pragma unroll
        for (int u = 0; u < 16; ++u) {
            float m = -3.0e38f;
            #pragma unroll
            for (int k = 0; k < 8; ++k) {
                float raw = fmaxf(0.f, fmaf((float)v[u][k], -0.5f, 0.5f));
                m = fmaxf(m, fmaf(-gk[k], raw, ak[k]));
            }
            cmx[jt * 128 + u * 8 + (t >> 5)][t & 31] = m;
        }
    }
    __syncthreads();

    // thread t owns local j = t: max over 32 i-group partials
    float m = -3.0e38f;
    #pragma unroll 8
    for (int k = 0; k < 32; ++k) m = fmaxf(m, cmx[t][k]);
    colmaxP[((size_t)n * NIP + ip) * SN + jc * 256 + t] = m;
}

// ---------------- small reduce kernels ----------------

__global__ __launch_bounds__(256) void r_g(const float* __restrict__ rowmaxP,
                                           float* __restrict__ grow) {
    int idx = blockIdx.x * 256 + threadIdx.x;
    int n = idx / SN, i = idx - n * SN;
    float m = -3.0e38f;
    for (int ch = 0; ch < NCHUNK; ++ch)
        m = fmaxf(m, rowmaxP[(size_t)(n * NCHUNK + ch) * SN + i]);
    float mr = fmaxf(0.f, (1.f - m) * 0.5f);
    grow[idx] = 10.f / (mr + 1e-5f);
}

__global__ __launch_bounds__(256) void r_alpha(const float* __restrict__ rowsumP,
                                               float* __restrict__ alpha, int nch) {
    int idx = blockIdx.x * 256 + threadIdx.x;
    int n = idx / SN, i = idx - n * SN;
    float s = 0.f;
    for (int ch = 0; ch < nch; ++ch)
        s += rowsumP[(size_t)(n * nch + ch) * SN + i];
    alpha[idx] = 10.f - logf(s);
}

__global__ __launch_bounds__(256) void r_colfin(const float* __restrict__ colmaxP,
                                                float* __restrict__ bsum, int nch) {
    int idx = blockIdx.x * 256 + threadIdx.x;
    int n = idx / SN, j = idx - n * SN;
    float m = -3.0e38f;
    for (int ch = 0; ch < nch; ++ch)
        m = fmaxf(m, colmaxP[(size_t)(n * nch + ch) * SN + j]);
    float v = expf(m);
    #pragma unroll
    for (int d = 1; d < 64; d <<= 1) v += __shfl_xor(v, d, 64);
    __shared__ float sb[4];
    if ((threadIdx.x & 63) == 0) sb[threadIdx.x >> 6] = v;
    __syncthreads();
    if (threadIdx.x == 0) bsum[blockIdx.x] = sb[0] + sb[1] + sb[2] + sb[3];
}

__global__ __launch_bounds__(64) void r_loss(const float* __restrict__ bsum,
                                             float* __restrict__ out) {
    int t = threadIdx.x;
    float v = (t < 50) ? bsum[t] : 0.f;
    float v0 = (t < 25) ? v : 0.f;
    float v1 = (t >= 25 && t < 50) ? v : 0.f;
    #pragma unroll
    for (int d = 1; d < 64; d <<= 1) {
        v0 += __shfl_xor(v0, d, 64);
        v1 += __shfl_xor(v1, d, 64);
    }
    if (t == 0) {
        float cs0 = v0 * (1.0f / SN), cs1 = v1 * (1.0f / SN);
        out[0] = -0.5f * (logf(cs0) + logf(cs1));
    }
}

// ---------------- launch ----------------

extern "C" void kernel_launch(void* const* d_in, const int* in_sizes, int n_in,
                              void* d_out, int out_size, void* d_ws, size_t ws_size,
                              hipStream_t stream) {
    const float* I = (const float*)d_in[0];
    const float* T = (const float*)d_in[1];
    float* out = (float*)d_out;

    float* wsf = (float*)d_ws;
    float* meanT = wsf;                         // 256
    float* grow  = meanT + 256;                 // 12800 (fallback only)
    float* alpha = grow + 12800;                // 12800 (fallback only)
    float* rowmaxP = alpha + 12800;             // 64000 (5 chunks)
    float* sumP  = rowmaxP + 64000;             // 320000 (25 chunks; fallback 5)
    float* colmaxP = sumP + 320000;             // 320000 (25 panels; fallback 5)
    float* bsum = colmaxP + 320000;             // 64
    f16* Ah = (f16*)(bsum + 64);                // 2*6400*256 f16
    f16* Bh = Ah + (size_t)NBATCH * SN * CN;
    f16* Sws = Bh + (size_t)NBATCH * SN * CN;   // 2*6400*6400 f16 = 163.84 MB

    const size_t NEEDED = (size_t)(256 + 12800 + 12800 + 64000
                                   + 320000 + 320000 + 64) * 4
                        + (size_t)2 * NBATCH * SN * CN * 2
                        + (size_t)NBATCH * SN * SN * 2;
    const bool cached = ws_size >= NEEDED;

    k_meanT<<<256, 256, 0, stream>>>(T, meanT);
    k_prep<<<dim3(100, 1, 2), 256, 0, stream>>>(I, meanT, Ah);
    k_prep<<<dim3(100, 1, 2), 256, 0, stream>>>(T, meanT, Bh);

    dim3 gg(NTILES, NCHUNK, NBATCH);
    if (cached) {
        k_gemm_s<<<gg, 512, 0, stream>>>(Ah, Bh, rowmaxP, Sws);
        k_rowsum<<<dim3(NJC, NIP, NBATCH), 256, 0, stream>>>(Sws, rowmaxP, sumP);
        k_colmax<<<dim3(NJC, NIP, NBATCH), 256, 0, stream>>>(Sws, rowmaxP, sumP, colmaxP);
        r_colfin<<<50, 256, 0, stream>>>(colmaxP, bsum, NIP);
    } else {
        k_gemm3<0><<<gg, 512, 0, stream>>>(Ah, Bh, nullptr, nullptr, rowmaxP);
        r_g<<<50, 256, 0, stream>>>(rowmaxP, grow);
        k_gemm3<1><<<gg, 512, 0, stream>>>(Ah, Bh, grow, nullptr, sumP);
        r_alpha<<<50, 256, 0, stream>>>(sumP, alpha, NCHUNK);
        k_gemm3<2><<<gg, 512, 0, stream>>>(Bh, Ah, grow, alpha, colmaxP);
        r_colfin<<<50, 256, 0, stream>>>(colmaxP, bsum, NCHUNK);
    }
    r_loss<<<1, 64, 0, stream>>>(bsum, out);
}